// Round 2
// baseline (126.236 us; speedup 1.0000x reference)
//
#include <hip/hip_runtime.h>

#define NODES 4096
#define NDIM  512
#define HID   4096

typedef __attribute__((ext_vector_type(8))) short bf16x8;
typedef __attribute__((ext_vector_type(4))) float f32x4;

__device__ __forceinline__ float b2f(short v) {
  union { unsigned int u; float f; } c;
  c.u = ((unsigned int)(unsigned short)v) << 16;
  return c.f;
}
__device__ __forceinline__ short f2b(float f) {
  union { float f; unsigned int u; } c; c.f = f;
  unsigned int r = c.u + 0x7fffu + ((c.u >> 16) & 1u);  // round-nearest-even
  return (short)(r >> 16);
}

// ---- K0: fused prep: cast x->bf16 | transpose+cast W1 | init accumulators ----
__global__ __launch_bounds__(256) void k_prep(const float* __restrict__ x,
                                              const float* __restrict__ W1,
                                              const float* __restrict__ b2,
                                              const float* __restrict__ b3,
                                              short* __restrict__ xb,
                                              short* __restrict__ w1t,
                                              float* __restrict__ aacc,
                                              float* __restrict__ svec,
                                              float* __restrict__ uacc) {
  __shared__ float tile[32][33];
  int b = blockIdx.x;
  if (b < 2048) {                       // cast x (4096x512 fp32 -> bf16)
    int i = (b * 256 + threadIdx.x) * 4;
    float4 v = *(const float4*)(x + i);
    short4 o;
    o.x = f2b(v.x); o.y = f2b(v.y); o.z = f2b(v.z); o.w = f2b(v.w);
    *(short4*)(xb + i) = o;
  } else if (b < 4096) {                // transpose W1 [512][4096] -> [4096][512] bf16
    int t = b - 2048;
    int n0 = (t & 127) * 32;
    int k0 = (t >> 7) * 32;
    int tx = threadIdx.x & 31, ty = threadIdx.x >> 5;
    #pragma unroll
    for (int j = 0; j < 4; ++j) {
      int kk = ty + j * 8;
      tile[kk][tx] = W1[(size_t)(k0 + kk) * HID + n0 + tx];
    }
    __syncthreads();
    #pragma unroll
    for (int j = 0; j < 4; ++j) {
      int nn = ty + j * 8;
      w1t[(size_t)(n0 + nn) * NDIM + k0 + tx] = f2b(tile[tx][nn]);
    }
  } else {                              // init: a=0, s=N*b2, u=b3
    int j = (b - 4096) * 256 + threadIdx.x;
    aacc[j] = 0.0f;
    svec[j] = (float)NODES * b2[j];
    uacc[j] = b3[j];
  }
}

// ---- K1: A = relu(x @ W1 + b1) (bf16 MFMA), fused column sums ----
// 128x128 tile, BK=32, double-buffered LDS, 1 barrier/K-step, repacked epilogue.
__global__ __launch_bounds__(256) void k_gemm1(const short* __restrict__ xb,
                                               const short* __restrict__ w1t,
                                               const float* __restrict__ b1,
                                               short* __restrict__ Aout,
                                               float* __restrict__ colsum) {
  __shared__ short smem[16384];         // 32 KB: A dbuf @0, B dbuf @16384B; reused for repack
  __shared__ float csum[128];

  const int tid  = threadIdx.x;
  const int lane = tid & 63;
  const int w    = tid >> 6;
  const int wr   = w >> 1, wc = w & 1;
  const int brow = blockIdx.y * 128, bcol = blockIdx.x * 128;

  f32x4 acc[4][4];
  #pragma unroll
  for (int i = 0; i < 4; ++i)
    #pragma unroll
    for (int j = 0; j < 4; ++j)
      acc[i][j] = (f32x4){0.f, 0.f, 0.f, 0.f};

  if (tid < 128) csum[tid] = 0.f;

  const int fr = lane & 15;
  const int fk = (lane >> 4) * 8;

  auto STAGE = [&](int buf, int kt) {
    #pragma unroll
    for (int j = 0; j < 2; ++j) {
      int off = (j * 4 + w) * 1024 + lane * 16;   // byte offset in 8 KB tile
      int row = off >> 6, ce = (off & 63) >> 1;   // LDS linear == global row-major
      const short* ga = xb + (size_t)(brow + row) * NDIM + kt * 32 + ce;
      __builtin_amdgcn_global_load_lds(
          (const __attribute__((address_space(1))) void*)ga,
          (__attribute__((address_space(3))) void*)((char*)smem + buf * 8192 + off),
          16, 0, 0);
      const short* gb = w1t + (size_t)(bcol + row) * NDIM + kt * 32 + ce;
      __builtin_amdgcn_global_load_lds(
          (const __attribute__((address_space(1))) void*)gb,
          (__attribute__((address_space(3))) void*)((char*)smem + 16384 + buf * 8192 + off),
          16, 0, 0);
    }
  };

  STAGE(0, 0);
  __syncthreads();                       // drains vmcnt(0): tile 0 ready
  int cur = 0;
  #pragma unroll 1
  for (int kt = 0; kt < NDIM / 32 - 1; ++kt) {
    STAGE(cur ^ 1, kt + 1);              // next tile in flight under MFMA
    bf16x8 af[4], bfr[4];
    const short* Ab = (const short*)((char*)smem + cur * 8192);
    const short* Bb = (const short*)((char*)smem + 16384 + cur * 8192);
    #pragma unroll
    for (int mi = 0; mi < 4; ++mi)
      af[mi] = *(const bf16x8*)(Ab + (wr * 64 + mi * 16 + fr) * 32 + fk);
    #pragma unroll
    for (int ni = 0; ni < 4; ++ni)
      bfr[ni] = *(const bf16x8*)(Bb + (wc * 64 + ni * 16 + fr) * 32 + fk);
    #pragma unroll
    for (int mi = 0; mi < 4; ++mi)
      #pragma unroll
      for (int ni = 0; ni < 4; ++ni)
        acc[mi][ni] = __builtin_amdgcn_mfma_f32_16x16x32_bf16(af[mi], bfr[ni],
                                                              acc[mi][ni], 0, 0, 0);
    __syncthreads();                     // drains vmcnt(0): next tile ready, cur free
    cur ^= 1;
  }
  {                                      // last K-tile, no prefetch
    bf16x8 af[4], bfr[4];
    const short* Ab = (const short*)((char*)smem + cur * 8192);
    const short* Bb = (const short*)((char*)smem + 16384 + cur * 8192);
    #pragma unroll
    for (int mi = 0; mi < 4; ++mi)
      af[mi] = *(const bf16x8*)(Ab + (wr * 64 + mi * 16 + fr) * 32 + fk);
    #pragma unroll
    for (int ni = 0; ni < 4; ++ni)
      bfr[ni] = *(const bf16x8*)(Bb + (wc * 64 + ni * 16 + fr) * 32 + fk);
    #pragma unroll
    for (int mi = 0; mi < 4; ++mi)
      #pragma unroll
      for (int ni = 0; ni < 4; ++ni)
        acc[mi][ni] = __builtin_amdgcn_mfma_f32_16x16x32_bf16(af[mi], bfr[ni],
                                                              acc[mi][ni], 0, 0, 0);
  }
  __syncthreads();                       // everyone done with dbuf; reuse smem for repack

  // epilogue: bias + relu + csum; pack bf16 tile in LDS (XOR-swizzled rows)
  const int rbase = (lane >> 4) * 4;     // C/D: col = lane&15, row = (lane>>4)*4 + reg
  #pragma unroll
  for (int ni = 0; ni < 4; ++ni) {
    int lcol = wc * 64 + ni * 16 + fr;
    float bias = b1[bcol + lcol];
    float cl = 0.f;
    #pragma unroll
    for (int mi = 0; mi < 4; ++mi) {
      #pragma unroll
      for (int r = 0; r < 4; ++r) {
        float v = acc[mi][ni][r] + bias;
        v = fmaxf(v, 0.f);
        cl += v;
        int lrow = wr * 64 + mi * 16 + rbase + r;
        int boff = (lrow * 256 + lcol * 2) ^ ((lrow & 7) << 4);
        *(short*)((char*)smem + boff) = f2b(v);
      }
    }
    atomicAdd(&csum[lcol], cl);
  }
  __syncthreads();
  // coalesced store: 1024 chunks x 16 B, waves write 1 KB contiguous
  #pragma unroll
  for (int i = 0; i < 8; ++i) {
    int c = i * 256 + tid;
    int lrow = c >> 4;
    int boff = (c * 16) ^ ((lrow & 7) << 4);
    bf16x8 vv = *(const bf16x8*)((char*)smem + boff);
    *(bf16x8*)(Aout + (size_t)(brow + lrow) * HID + bcol + (c & 15) * 8) = vv;
  }
  if (tid < 128) atomicAdd(&colsum[bcol + tid], csum[tid]);
}

// ---- K2/K5: vout[col] += sum_i vin[i] * W[i][col]  (W: [4096][4096] fp32) ----
__global__ __launch_bounds__(256) void k_gemv_at(const float* __restrict__ W,
                                                 const float* __restrict__ vin,
                                                 float* __restrict__ vout) {
  const int col = blockIdx.x * 1024 + threadIdx.x * 4;
  const int r0  = blockIdx.y * 32;
  float4 accv = {0.f, 0.f, 0.f, 0.f};
  const float* base = W + (size_t)r0 * HID + col;
  #pragma unroll 8
  for (int i = 0; i < 32; ++i) {
    float vi = vin[r0 + i];
    float4 wv = *(const float4*)(base + (size_t)i * HID);
    accv.x += vi * wv.x; accv.y += vi * wv.y;
    accv.z += vi * wv.z; accv.w += vi * wv.w;
  }
  atomicAdd(&vout[col + 0], accv.x);
  atomicAdd(&vout[col + 1], accv.y);
  atomicAdd(&vout[col + 2], accv.z);
  atomicAdd(&vout[col + 3], accv.w);
}

// ---- K3: t[row] = W2[row,:] . s ; extra block computes beta = b2 . s ----
__global__ __launch_bounds__(256) void k_gemv_row(const float* __restrict__ W,
                                                  const float* __restrict__ vin,
                                                  const float* __restrict__ b2,
                                                  float* __restrict__ vout,
                                                  float* __restrict__ beta) {
  __shared__ float red[4];
  if (blockIdx.x == HID / 4) {           // beta block
    float p = 0.f;
    for (int j = threadIdx.x; j < HID; j += 256) p += b2[j] * vin[j];
    #pragma unroll
    for (int o = 32; o > 0; o >>= 1) p += __shfl_down(p, o);
    int lane = threadIdx.x & 63, w = threadIdx.x >> 6;
    if (lane == 0) red[w] = p;
    __syncthreads();
    if (threadIdx.x == 0) beta[0] = red[0] + red[1] + red[2] + red[3];
    return;
  }
  int w = threadIdx.x >> 6, lane = threadIdx.x & 63;
  int row = blockIdx.x * 4 + w;
  const float* base = W + (size_t)row * HID;
  float p = 0.f;
  #pragma unroll 4
  for (int j = lane * 4; j < HID; j += 256) {
    float4 wv = *(const float4*)(base + j);
    float4 sv = *(const float4*)(vin + j);
    p += wv.x * sv.x + wv.y * sv.y + wv.z * sv.z + wv.w * sv.w;
  }
  #pragma unroll
  for (int o = 32; o > 0; o >>= 1) p += __shfl_down(p, o);
  if (lane == 0) vout[row] = p;
}

// ---- K4: kv[row] = A[row,:] . t + beta   (A bf16) ----
__global__ __launch_bounds__(256) void k_kv(const short* __restrict__ A,
                                            const float* __restrict__ t,
                                            const float* __restrict__ beta,
                                            float* __restrict__ kv) {
  int w = threadIdx.x >> 6, lane = threadIdx.x & 63;
  int row = blockIdx.x * 4 + w;
  const short* base = A + (size_t)row * HID;
  float p = 0.f;
  #pragma unroll
  for (int j = lane * 8; j < HID; j += 512) {
    bf16x8 av = *(const bf16x8*)(base + j);
    float4 t0 = *(const float4*)(t + j);
    float4 t1 = *(const float4*)(t + j + 4);
    p += b2f(av[0]) * t0.x + b2f(av[1]) * t0.y + b2f(av[2]) * t0.z + b2f(av[3]) * t0.w
       + b2f(av[4]) * t1.x + b2f(av[5]) * t1.y + b2f(av[6]) * t1.z + b2f(av[7]) * t1.w;
  }
  #pragma unroll
  for (int o = 32; o > 0; o >>= 1) p += __shfl_down(p, o);
  if (lane == 0) kv[row] = p + beta[0];
}

// ---- K6: out = relu(uacc) . W4 + b4 ----
__global__ __launch_bounds__(256) void k_final(const float* __restrict__ uacc,
                                               const float* __restrict__ W4,
                                               const float* __restrict__ b4,
                                               float* __restrict__ out) {
  __shared__ float red[4];
  float p = 0.f;
  for (int j = threadIdx.x; j < HID; j += 256) {
    float uv = uacc[j];
    uv = uv > 0.f ? uv : 0.f;
    p += uv * W4[j];
  }
  #pragma unroll
  for (int o = 32; o > 0; o >>= 1) p += __shfl_down(p, o);
  int lane = threadIdx.x & 63, w = threadIdx.x >> 6;
  if (lane == 0) red[w] = p;
  __syncthreads();
  if (threadIdx.x == 0) out[0] = red[0] + red[1] + red[2] + red[3] + b4[0];
}

extern "C" void kernel_launch(void* const* d_in, const int* in_sizes, int n_in,
                              void* d_out, int out_size, void* d_ws, size_t ws_size,
                              hipStream_t stream) {
  const float* x  = (const float*)d_in[0];
  // d_in[1] = edge_index (dead in the reference)
  const float* W1 = (const float*)d_in[2];
  const float* b1 = (const float*)d_in[3];
  const float* W2 = (const float*)d_in[4];
  const float* b2 = (const float*)d_in[5];
  const float* W3 = (const float*)d_in[6];
  const float* b3 = (const float*)d_in[7];
  const float* W4 = (const float*)d_in[8];
  const float* b4 = (const float*)d_in[9];
  float* out = (float*)d_out;

  char* ws = (char*)d_ws;
  short* Abf  = (short*)(ws);                 // 32 MB
  short* xb   = (short*)(ws + 33554432);      // 4 MB
  short* w1t  = (short*)(ws + 37748736);      // 4 MB
  float* aacc = (float*)(ws + 41943040);
  float* svec = (float*)(ws + 41959424);
  float* tvec = (float*)(ws + 41975808);
  float* kvv  = (float*)(ws + 41992192);
  float* uacc = (float*)(ws + 42008576);
  float* beta = (float*)(ws + 42024960);

  k_prep    <<<dim3(4112),     dim3(256), 0, stream>>>(x, W1, b2, b3, xb, w1t, aacc, svec, uacc);
  k_gemm1   <<<dim3(32, 32),   dim3(256), 0, stream>>>(xb, w1t, b1, Abf, aacc);
  k_gemv_at <<<dim3(4, 128),   dim3(256), 0, stream>>>(W2, aacc, svec);
  k_gemv_row<<<dim3(1025),     dim3(256), 0, stream>>>(W2, svec, b2, tvec, beta);
  k_kv      <<<dim3(1024),     dim3(256), 0, stream>>>(Abf, tvec, beta, kvv);
  k_gemv_at <<<dim3(4, 128),   dim3(256), 0, stream>>>(W3, kvv, uacc);
  k_final   <<<dim3(1),        dim3(256), 0, stream>>>(uacc, W4, b4, out);
}

// Round 3
// 121.690 us; speedup vs baseline: 1.0374x; 1.0374x over previous
//
#include <hip/hip_runtime.h>

#define NODES 4096
#define NDIM  512
#define HID   4096

typedef __attribute__((ext_vector_type(8))) short bf16x8;
typedef __attribute__((ext_vector_type(4))) float f32x4;

__device__ __forceinline__ float b2f(short v) {
  union { unsigned int u; float f; } c;
  c.u = ((unsigned int)(unsigned short)v) << 16;
  return c.f;
}
__device__ __forceinline__ short f2b(float f) {
  union { float f; unsigned int u; } c; c.f = f;
  unsigned int r = c.u + 0x7fffu + ((c.u >> 16) & 1u);  // round-nearest-even
  return (short)(r >> 16);
}

// ---- K0: fused prep: cast x->bf16 | transpose+cast W1 | init accumulators ----
__global__ __launch_bounds__(256) void k_prep(const float* __restrict__ x,
                                              const float* __restrict__ W1,
                                              const float* __restrict__ b2,
                                              const float* __restrict__ b3,
                                              short* __restrict__ xb,
                                              short* __restrict__ w1t,
                                              float* __restrict__ aacc,
                                              float* __restrict__ svec,
                                              float* __restrict__ uacc) {
  __shared__ float tile[32][33];
  int b = blockIdx.x;
  if (b < 2048) {                       // cast x (4096x512 fp32 -> bf16)
    int i = (b * 256 + threadIdx.x) * 4;
    float4 v = *(const float4*)(x + i);
    short4 o;
    o.x = f2b(v.x); o.y = f2b(v.y); o.z = f2b(v.z); o.w = f2b(v.w);
    *(short4*)(xb + i) = o;
  } else if (b < 4096) {                // transpose W1 [512][4096] -> [4096][512] bf16
    int t = b - 2048;
    int n0 = (t & 127) * 32;
    int k0 = (t >> 7) * 32;
    int tx = threadIdx.x & 31, ty = threadIdx.x >> 5;
    #pragma unroll
    for (int j = 0; j < 4; ++j) {
      int kk = ty + j * 8;
      tile[kk][tx] = W1[(size_t)(k0 + kk) * HID + n0 + tx];
    }
    __syncthreads();
    #pragma unroll
    for (int j = 0; j < 4; ++j) {
      int nn = ty + j * 8;
      w1t[(size_t)(n0 + nn) * NDIM + k0 + tx] = f2b(tile[tx][nn]);
    }
  } else {                              // init: a=0, s=N*b2, u=b3
    int j = (b - 4096) * 256 + threadIdx.x;
    aacc[j] = 0.0f;
    svec[j] = (float)NODES * b2[j];
    uacc[j] = b3[j];
  }
}

// ---- K1: A = relu(x @ W1 + b1) (bf16 MFMA), fused column sums ----
// 128x128 tile, BK=32, stage-early dbuf (1 barrier/K-step), direct-store epilogue.
__global__ __launch_bounds__(256) void k_gemm1(const short* __restrict__ xb,
                                               const short* __restrict__ w1t,
                                               const float* __restrict__ b1,
                                               short* __restrict__ Aout,
                                               float* __restrict__ colsum) {
  __shared__ short smem[16384];         // 32 KB: A dbuf @0, B dbuf @16384 B
  __shared__ float csum[128];

  const int tid  = threadIdx.x;
  const int lane = tid & 63;
  const int w    = tid >> 6;
  const int wr   = w >> 1, wc = w & 1;

  // XCD-aware swizzle: 1024 blocks, 8 XCDs, 128 consecutive ids per XCD.
  // Each XCD covers 4 full row-bands (by) x all 32 col-blocks -> xb panels
  // (4 x 128 KB) + whole w1t stay hot in that XCD's 4 MB L2.
  int swz = (blockIdx.x & 7) * 128 + (blockIdx.x >> 3);
  const int brow = (swz >> 5) * 128, bcol = (swz & 31) * 128;

  f32x4 acc[4][4];
  #pragma unroll
  for (int i = 0; i < 4; ++i)
    #pragma unroll
    for (int j = 0; j < 4; ++j)
      acc[i][j] = (f32x4){0.f, 0.f, 0.f, 0.f};

  if (tid < 128) csum[tid] = 0.f;

  const int fr = lane & 15;
  const int fk = (lane >> 4) * 8;

  auto STAGE = [&](int buf, int kt) {
    #pragma unroll
    for (int j = 0; j < 2; ++j) {
      int off = (j * 4 + w) * 1024 + lane * 16;   // byte offset in 8 KB tile
      int row = off >> 6, ce = (off & 63) >> 1;   // LDS linear == global row-major
      const short* ga = xb + (size_t)(brow + row) * NDIM + kt * 32 + ce;
      __builtin_amdgcn_global_load_lds(
          (const __attribute__((address_space(1))) void*)ga,
          (__attribute__((address_space(3))) void*)((char*)smem + buf * 8192 + off),
          16, 0, 0);
      const short* gb = w1t + (size_t)(bcol + row) * NDIM + kt * 32 + ce;
      __builtin_amdgcn_global_load_lds(
          (const __attribute__((address_space(1))) void*)gb,
          (__attribute__((address_space(3))) void*)((char*)smem + 16384 + buf * 8192 + off),
          16, 0, 0);
    }
  };

  STAGE(0, 0);
  __syncthreads();                       // tile 0 ready (drains vmcnt)
  int cur = 0;
  #pragma unroll 1
  for (int kt = 0; kt < NDIM / 32 - 1; ++kt) {
    STAGE(cur ^ 1, kt + 1);              // next tile in flight under MFMA
    bf16x8 af[4], bfr[4];
    const short* Ab = (const short*)((char*)smem + cur * 8192);
    const short* Bb = (const short*)((char*)smem + 16384 + cur * 8192);
    #pragma unroll
    for (int mi = 0; mi < 4; ++mi)
      af[mi] = *(const bf16x8*)(Ab + (wr * 64 + mi * 16 + fr) * 32 + fk);
    #pragma unroll
    for (int ni = 0; ni < 4; ++ni)
      bfr[ni] = *(const bf16x8*)(Bb + (wc * 64 + ni * 16 + fr) * 32 + fk);
    #pragma unroll
    for (int mi = 0; mi < 4; ++mi)
      #pragma unroll
      for (int ni = 0; ni < 4; ++ni)
        acc[mi][ni] = __builtin_amdgcn_mfma_f32_16x16x32_bf16(af[mi], bfr[ni],
                                                              acc[mi][ni], 0, 0, 0);
    __syncthreads();                     // next tile ready, cur buffer free
    cur ^= 1;
  }
  {                                      // last K-tile, no prefetch
    bf16x8 af[4], bfr[4];
    const short* Ab = (const short*)((char*)smem + cur * 8192);
    const short* Bb = (const short*)((char*)smem + 16384 + cur * 8192);
    #pragma unroll
    for (int mi = 0; mi < 4; ++mi)
      af[mi] = *(const bf16x8*)(Ab + (wr * 64 + mi * 16 + fr) * 32 + fk);
    #pragma unroll
    for (int ni = 0; ni < 4; ++ni)
      bfr[ni] = *(const bf16x8*)(Bb + (wc * 64 + ni * 16 + fr) * 32 + fk);
    #pragma unroll
    for (int mi = 0; mi < 4; ++mi)
      #pragma unroll
      for (int ni = 0; ni < 4; ++ni)
        acc[mi][ni] = __builtin_amdgcn_mfma_f32_16x16x32_bf16(af[mi], bfr[ni],
                                                              acc[mi][ni], 0, 0, 0);
  }

  // epilogue: bias + relu + direct bf16 stores + column partial sums
  const int rbase = (lane >> 4) * 4;     // C/D: col = lane&15, row = (lane>>4)*4 + reg
  #pragma unroll
  for (int ni = 0; ni < 4; ++ni) {
    int lcol = wc * 64 + ni * 16 + fr;
    int col  = bcol + lcol;
    float bias = b1[col];
    float cl = 0.f;
    #pragma unroll
    for (int mi = 0; mi < 4; ++mi) {
      #pragma unroll
      for (int r = 0; r < 4; ++r) {
        float v = acc[mi][ni][r] + bias;
        v = fmaxf(v, 0.f);
        cl += v;
        int grow = brow + wr * 64 + mi * 16 + rbase + r;
        Aout[(size_t)grow * HID + col] = f2b(v);
      }
    }
    atomicAdd(&csum[lcol], cl);
  }
  __syncthreads();
  if (tid < 128) atomicAdd(&colsum[bcol + tid], csum[tid]);
}

// ---- K2/K5: vout[col] += sum_i vin[i] * W[i][col]  (W: [4096][4096] fp32) ----
__global__ __launch_bounds__(256) void k_gemv_at(const float* __restrict__ W,
                                                 const float* __restrict__ vin,
                                                 float* __restrict__ vout) {
  const int col = blockIdx.x * 1024 + threadIdx.x * 4;
  const int r0  = blockIdx.y * 32;
  float4 accv = {0.f, 0.f, 0.f, 0.f};
  const float* base = W + (size_t)r0 * HID + col;
  #pragma unroll 16
  for (int i = 0; i < 32; ++i) {
    float vi = vin[r0 + i];
    float4 wv = *(const float4*)(base + (size_t)i * HID);
    accv.x += vi * wv.x; accv.y += vi * wv.y;
    accv.z += vi * wv.z; accv.w += vi * wv.w;
  }
  atomicAdd(&vout[col + 0], accv.x);
  atomicAdd(&vout[col + 1], accv.y);
  atomicAdd(&vout[col + 2], accv.z);
  atomicAdd(&vout[col + 3], accv.w);
}

// ---- K3: t[row] = W2[row,:] . s ; extra block computes beta = b2 . s ----
__global__ __launch_bounds__(256) void k_gemv_row(const float* __restrict__ W,
                                                  const float* __restrict__ vin,
                                                  const float* __restrict__ b2,
                                                  float* __restrict__ vout,
                                                  float* __restrict__ beta) {
  __shared__ float red[4];
  if (blockIdx.x == HID / 4) {           // beta block
    float p = 0.f;
    for (int j = threadIdx.x; j < HID; j += 256) p += b2[j] * vin[j];
    #pragma unroll
    for (int o = 32; o > 0; o >>= 1) p += __shfl_down(p, o);
    int lane = threadIdx.x & 63, w = threadIdx.x >> 6;
    if (lane == 0) red[w] = p;
    __syncthreads();
    if (threadIdx.x == 0) beta[0] = red[0] + red[1] + red[2] + red[3];
    return;
  }
  int w = threadIdx.x >> 6, lane = threadIdx.x & 63;
  int row = blockIdx.x * 4 + w;
  const float* base = W + (size_t)row * HID;
  float p = 0.f;
  #pragma unroll 8
  for (int j = lane * 4; j < HID; j += 256) {
    float4 wv = *(const float4*)(base + j);
    float4 sv = *(const float4*)(vin + j);
    p += wv.x * sv.x + wv.y * sv.y + wv.z * sv.z + wv.w * sv.w;
  }
  #pragma unroll
  for (int o = 32; o > 0; o >>= 1) p += __shfl_down(p, o);
  if (lane == 0) vout[row] = p;
}

// ---- K4: kv[row] = A[row,:] . t + beta   (A bf16) ----
__global__ __launch_bounds__(256) void k_kv(const short* __restrict__ A,
                                            const float* __restrict__ t,
                                            const float* __restrict__ beta,
                                            float* __restrict__ kv) {
  int w = threadIdx.x >> 6, lane = threadIdx.x & 63;
  int row = blockIdx.x * 4 + w;
  const short* base = A + (size_t)row * HID;
  float p = 0.f;
  #pragma unroll
  for (int j = lane * 8; j < HID; j += 512) {
    bf16x8 av = *(const bf16x8*)(base + j);
    float4 t0 = *(const float4*)(t + j);
    float4 t1 = *(const float4*)(t + j + 4);
    p += b2f(av[0]) * t0.x + b2f(av[1]) * t0.y + b2f(av[2]) * t0.z + b2f(av[3]) * t0.w
       + b2f(av[4]) * t1.x + b2f(av[5]) * t1.y + b2f(av[6]) * t1.z + b2f(av[7]) * t1.w;
  }
  #pragma unroll
  for (int o = 32; o > 0; o >>= 1) p += __shfl_down(p, o);
  if (lane == 0) kv[row] = p + beta[0];
}

// ---- K6: out = relu(uacc) . W4 + b4 ----
__global__ __launch_bounds__(256) void k_final(const float* __restrict__ uacc,
                                               const float* __restrict__ W4,
                                               const float* __restrict__ b4,
                                               float* __restrict__ out) {
  __shared__ float red[4];
  float p = 0.f;
  for (int j = threadIdx.x; j < HID; j += 256) {
    float uv = uacc[j];
    uv = uv > 0.f ? uv : 0.f;
    p += uv * W4[j];
  }
  #pragma unroll
  for (int o = 32; o > 0; o >>= 1) p += __shfl_down(p, o);
  int lane = threadIdx.x & 63, w = threadIdx.x >> 6;
  if (lane == 0) red[w] = p;
  __syncthreads();
  if (threadIdx.x == 0) out[0] = red[0] + red[1] + red[2] + red[3] + b4[0];
}

extern "C" void kernel_launch(void* const* d_in, const int* in_sizes, int n_in,
                              void* d_out, int out_size, void* d_ws, size_t ws_size,
                              hipStream_t stream) {
  const float* x  = (const float*)d_in[0];
  // d_in[1] = edge_index (dead in the reference)
  const float* W1 = (const float*)d_in[2];
  const float* b1 = (const float*)d_in[3];
  const float* W2 = (const float*)d_in[4];
  const float* b2 = (const float*)d_in[5];
  const float* W3 = (const float*)d_in[6];
  const float* b3 = (const float*)d_in[7];
  const float* W4 = (const float*)d_in[8];
  const float* b4 = (const float*)d_in[9];
  float* out = (float*)d_out;

  char* ws = (char*)d_ws;
  short* Abf  = (short*)(ws);                 // 32 MB
  short* xb   = (short*)(ws + 33554432);      // 4 MB
  short* w1t  = (short*)(ws + 37748736);      // 4 MB
  float* aacc = (float*)(ws + 41943040);
  float* svec = (float*)(ws + 41959424);
  float* tvec = (float*)(ws + 41975808);
  float* kvv  = (float*)(ws + 41992192);
  float* uacc = (float*)(ws + 42008576);
  float* beta = (float*)(ws + 42024960);

  k_prep    <<<dim3(4112),     dim3(256), 0, stream>>>(x, W1, b2, b3, xb, w1t, aacc, svec, uacc);
  k_gemm1   <<<dim3(1024),     dim3(256), 0, stream>>>(xb, w1t, b1, Abf, aacc);
  k_gemv_at <<<dim3(4, 128),   dim3(256), 0, stream>>>(W2, aacc, svec);
  k_gemv_row<<<dim3(1025),     dim3(256), 0, stream>>>(W2, svec, b2, tvec, beta);
  k_kv      <<<dim3(1024),     dim3(256), 0, stream>>>(Abf, tvec, beta, kvv);
  k_gemv_at <<<dim3(4, 128),   dim3(256), 0, stream>>>(W3, kvv, uacc);
  k_final   <<<dim3(1),        dim3(256), 0, stream>>>(uacc, W4, b4, out);
}

// Round 4
// 104.450 us; speedup vs baseline: 1.2086x; 1.1651x over previous
//
#include <hip/hip_runtime.h>

#define NODES 4096
#define NDIM  512
#define HID   4096

typedef __attribute__((ext_vector_type(8))) short bf16x8;
typedef __attribute__((ext_vector_type(4))) float f32x4;

__device__ __forceinline__ float b2f(short v) {
  union { unsigned int u; float f; } c;
  c.u = ((unsigned int)(unsigned short)v) << 16;
  return c.f;
}
__device__ __forceinline__ short f2b(float f) {
  union { float f; unsigned int u; } c; c.f = f;
  unsigned int r = c.u + 0x7fffu + ((c.u >> 16) & 1u);  // round-nearest-even
  return (short)(r >> 16);
}

// ---- K0: fused prep: cast x->bf16 | transpose+cast W1 | init accumulators ----
__global__ __launch_bounds__(256) void k_prep(const float* __restrict__ x,
                                              const float* __restrict__ W1,
                                              const float* __restrict__ b2,
                                              const float* __restrict__ b3,
                                              short* __restrict__ xb,
                                              short* __restrict__ w1t,
                                              float* __restrict__ aacc,
                                              float* __restrict__ svec,
                                              float* __restrict__ uacc) {
  __shared__ float tile[32][33];
  int b = blockIdx.x;
  if (b < 2048) {                       // cast x (4096x512 fp32 -> bf16)
    int i = (b * 256 + threadIdx.x) * 4;
    float4 v = *(const float4*)(x + i);
    short4 o;
    o.x = f2b(v.x); o.y = f2b(v.y); o.z = f2b(v.z); o.w = f2b(v.w);
    *(short4*)(xb + i) = o;
  } else if (b < 4096) {                // transpose W1 [512][4096] -> [4096][512] bf16
    int t = b - 2048;
    int n0 = (t & 127) * 32;
    int k0 = (t >> 7) * 32;
    int tx = threadIdx.x & 31, ty = threadIdx.x >> 5;
    #pragma unroll
    for (int j = 0; j < 4; ++j) {
      int kk = ty + j * 8;
      tile[kk][tx] = W1[(size_t)(k0 + kk) * HID + n0 + tx];
    }
    __syncthreads();
    #pragma unroll
    for (int j = 0; j < 4; ++j) {
      int nn = ty + j * 8;
      w1t[(size_t)(n0 + nn) * NDIM + k0 + tx] = f2b(tile[tx][nn]);
    }
  } else {                              // init: a=0, s=N*b2, u=b3
    int j = (b - 4096) * 256 + threadIdx.x;
    aacc[j] = 0.0f;
    svec[j] = (float)NODES * b2[j];
    uacc[j] = b3[j];
  }
}

// ---- K1: A = relu(x @ W1 + b1) (bf16 MFMA), fused column sums ----
// 128x128 tile, BK=32, double-buffered LDS with COUNTED vmcnt(4) pipeline:
// next tile's 4 global_load_lds stay in flight across barriers + MFMA (T3+T4).
__global__ __launch_bounds__(256) void k_gemm1(const short* __restrict__ xb,
                                               const short* __restrict__ w1t,
                                               const float* __restrict__ b1,
                                               short* __restrict__ Aout,
                                               float* __restrict__ colsum) {
  __shared__ short smem[16384];         // 32 KB: A dbuf @0, B dbuf @16384 B
  __shared__ float csum[128];

  const int tid  = threadIdx.x;
  const int lane = tid & 63;
  const int w    = tid >> 6;
  const int wr   = w >> 1, wc = w & 1;

  // XCD-aware swizzle (1024 blocks, %8==0 -> simple bijective form)
  int swz = (blockIdx.x & 7) * 128 + (blockIdx.x >> 3);
  const int brow = (swz >> 5) * 128, bcol = (swz & 31) * 128;

  f32x4 acc[4][4];
  #pragma unroll
  for (int i = 0; i < 4; ++i)
    #pragma unroll
    for (int j = 0; j < 4; ++j)
      acc[i][j] = (f32x4){0.f, 0.f, 0.f, 0.f};

  if (tid < 128) csum[tid] = 0.f;

  const int fr = lane & 15;
  const int fk = (lane >> 4) * 8;

  // Exactly 4 global_load_lds instructions per wave per call.
  auto STAGE = [&](int buf, int kt) {
    #pragma unroll
    for (int j = 0; j < 2; ++j) {
      int off = (j * 4 + w) * 1024 + lane * 16;   // byte offset in 8 KB tile
      int row = off >> 6, ce = (off & 63) >> 1;   // LDS linear == global row-major
      const short* ga = xb + (size_t)(brow + row) * NDIM + kt * 32 + ce;
      __builtin_amdgcn_global_load_lds(
          (const __attribute__((address_space(1))) void*)ga,
          (__attribute__((address_space(3))) void*)((char*)smem + buf * 8192 + off),
          16, 0, 0);
      const short* gb = w1t + (size_t)(bcol + row) * NDIM + kt * 32 + ce;
      __builtin_amdgcn_global_load_lds(
          (const __attribute__((address_space(1))) void*)gb,
          (__attribute__((address_space(3))) void*)((char*)smem + 16384 + buf * 8192 + off),
          16, 0, 0);
    }
  };

  auto COMPUTE = [&](int buf) {
    bf16x8 af[4], bfr[4];
    const short* Ab = (const short*)((char*)smem + buf * 8192);
    const short* Bb = (const short*)((char*)smem + 16384 + buf * 8192);
    #pragma unroll
    for (int mi = 0; mi < 4; ++mi)
      af[mi] = *(const bf16x8*)(Ab + (wr * 64 + mi * 16 + fr) * 32 + fk);
    #pragma unroll
    for (int ni = 0; ni < 4; ++ni)
      bfr[ni] = *(const bf16x8*)(Bb + (wc * 64 + ni * 16 + fr) * 32 + fk);
    #pragma unroll
    for (int mi = 0; mi < 4; ++mi)
      #pragma unroll
      for (int ni = 0; ni < 4; ++ni)
        acc[mi][ni] = __builtin_amdgcn_mfma_f32_16x16x32_bf16(af[mi], bfr[ni],
                                                              acc[mi][ni], 0, 0, 0);
  };

  STAGE(0, 0);                                     // 4 VMEM in flight (tile 0)
  #pragma unroll 1
  for (int kt = 0; kt < NDIM / 32 - 1; ++kt) {
    STAGE((kt + 1) & 1, kt + 1);                   // +4 VMEM (tile kt+1)
    asm volatile("s_waitcnt vmcnt(4)" ::: "memory");  // tile kt landed; kt+1 in flight
    __builtin_amdgcn_s_barrier();                  // all waves: tile kt visible
    COMPUTE(kt & 1);
    __builtin_amdgcn_s_barrier();                  // all waves done reading buf kt&1
  }
  asm volatile("s_waitcnt vmcnt(0)" ::: "memory"); // last tile landed
  __builtin_amdgcn_s_barrier();
  COMPUTE((NDIM / 32 - 1) & 1);

  // epilogue: bias + relu + direct bf16 stores + column partial sums
  const int rbase = (lane >> 4) * 4;     // C/D: col = lane&15, row = (lane>>4)*4 + reg
  #pragma unroll
  for (int ni = 0; ni < 4; ++ni) {
    int lcol = wc * 64 + ni * 16 + fr;
    int col  = bcol + lcol;
    float bias = b1[col];
    float cl = 0.f;
    #pragma unroll
    for (int mi = 0; mi < 4; ++mi) {
      #pragma unroll
      for (int r = 0; r < 4; ++r) {
        float v = acc[mi][ni][r] + bias;
        v = fmaxf(v, 0.f);
        cl += v;
        int grow = brow + wr * 64 + mi * 16 + rbase + r;
        Aout[(size_t)grow * HID + col] = f2b(v);
      }
    }
    atomicAdd(&csum[lcol], cl);
  }
  __syncthreads();
  if (tid < 128) atomicAdd(&colsum[bcol + tid], csum[tid]);
}

// ---- K2/K5: vout[col] += sum_i vin[i] * W[i][col]  (W: [4096][4096] fp32) ----
__global__ __launch_bounds__(256) void k_gemv_at(const float* __restrict__ W,
                                                 const float* __restrict__ vin,
                                                 float* __restrict__ vout) {
  const int col = blockIdx.x * 1024 + threadIdx.x * 4;
  const int r0  = blockIdx.y * 64;
  float4 accv = {0.f, 0.f, 0.f, 0.f};
  const float* base = W + (size_t)r0 * HID + col;
  #pragma unroll 16
  for (int i = 0; i < 64; ++i) {
    float vi = vin[r0 + i];
    float4 wv = *(const float4*)(base + (size_t)i * HID);
    accv.x += vi * wv.x; accv.y += vi * wv.y;
    accv.z += vi * wv.z; accv.w += vi * wv.w;
  }
  atomicAdd(&vout[col + 0], accv.x);
  atomicAdd(&vout[col + 1], accv.y);
  atomicAdd(&vout[col + 2], accv.z);
  atomicAdd(&vout[col + 3], accv.w);
}

// ---- K3: t[row] = W2[row,:] . s ; extra block computes beta = b2 . s ----
__global__ __launch_bounds__(256) void k_gemv_row(const float* __restrict__ W,
                                                  const float* __restrict__ vin,
                                                  const float* __restrict__ b2,
                                                  float* __restrict__ vout,
                                                  float* __restrict__ beta) {
  __shared__ float red[4];
  if (blockIdx.x == HID / 4) {           // beta block
    float p = 0.f;
    for (int j = threadIdx.x; j < HID; j += 256) p += b2[j] * vin[j];
    #pragma unroll
    for (int o = 32; o > 0; o >>= 1) p += __shfl_down(p, o);
    int lane = threadIdx.x & 63, w = threadIdx.x >> 6;
    if (lane == 0) red[w] = p;
    __syncthreads();
    if (threadIdx.x == 0) beta[0] = red[0] + red[1] + red[2] + red[3];
    return;
  }
  int w = threadIdx.x >> 6, lane = threadIdx.x & 63;
  int row = blockIdx.x * 4 + w;
  const float* base = W + (size_t)row * HID;
  float p = 0.f;
  #pragma unroll 8
  for (int j = lane * 4; j < HID; j += 256) {
    float4 wv = *(const float4*)(base + j);
    float4 sv = *(const float4*)(vin + j);
    p += wv.x * sv.x + wv.y * sv.y + wv.z * sv.z + wv.w * sv.w;
  }
  #pragma unroll
  for (int o = 32; o > 0; o >>= 1) p += __shfl_down(p, o);
  if (lane == 0) vout[row] = p;
}

// ---- K4: kv[row] = A[row,:] . t + beta   (A bf16) ----
__global__ __launch_bounds__(256) void k_kv(const short* __restrict__ A,
                                            const float* __restrict__ t,
                                            const float* __restrict__ beta,
                                            float* __restrict__ kv) {
  int w = threadIdx.x >> 6, lane = threadIdx.x & 63;
  int row = blockIdx.x * 4 + w;
  const short* base = A + (size_t)row * HID;
  float p = 0.f;
  #pragma unroll
  for (int j = lane * 8; j < HID; j += 512) {
    bf16x8 av = *(const bf16x8*)(base + j);
    float4 t0 = *(const float4*)(t + j);
    float4 t1 = *(const float4*)(t + j + 4);
    p += b2f(av[0]) * t0.x + b2f(av[1]) * t0.y + b2f(av[2]) * t0.z + b2f(av[3]) * t0.w
       + b2f(av[4]) * t1.x + b2f(av[5]) * t1.y + b2f(av[6]) * t1.z + b2f(av[7]) * t1.w;
  }
  #pragma unroll
  for (int o = 32; o > 0; o >>= 1) p += __shfl_down(p, o);
  if (lane == 0) kv[row] = p + beta[0];
}

// ---- K6: out = relu(uacc) . W4 + b4 ----
__global__ __launch_bounds__(256) void k_final(const float* __restrict__ uacc,
                                               const float* __restrict__ W4,
                                               const float* __restrict__ b4,
                                               float* __restrict__ out) {
  __shared__ float red[4];
  float p = 0.f;
  for (int j = threadIdx.x; j < HID; j += 256) {
    float uv = uacc[j];
    uv = uv > 0.f ? uv : 0.f;
    p += uv * W4[j];
  }
  #pragma unroll
  for (int o = 32; o > 0; o >>= 1) p += __shfl_down(p, o);
  int lane = threadIdx.x & 63, w = threadIdx.x >> 6;
  if (lane == 0) red[w] = p;
  __syncthreads();
  if (threadIdx.x == 0) out[0] = red[0] + red[1] + red[2] + red[3] + b4[0];
}

extern "C" void kernel_launch(void* const* d_in, const int* in_sizes, int n_in,
                              void* d_out, int out_size, void* d_ws, size_t ws_size,
                              hipStream_t stream) {
  const float* x  = (const float*)d_in[0];
  // d_in[1] = edge_index (dead in the reference)
  const float* W1 = (const float*)d_in[2];
  const float* b1 = (const float*)d_in[3];
  const float* W2 = (const float*)d_in[4];
  const float* b2 = (const float*)d_in[5];
  const float* W3 = (const float*)d_in[6];
  const float* b3 = (const float*)d_in[7];
  const float* W4 = (const float*)d_in[8];
  const float* b4 = (const float*)d_in[9];
  float* out = (float*)d_out;

  char* ws = (char*)d_ws;
  short* Abf  = (short*)(ws);                 // 32 MB
  short* xb   = (short*)(ws + 33554432);      // 4 MB
  short* w1t  = (short*)(ws + 37748736);      // 4 MB
  float* aacc = (float*)(ws + 41943040);
  float* svec = (float*)(ws + 41959424);
  float* tvec = (float*)(ws + 41975808);
  float* kvv  = (float*)(ws + 41992192);
  float* uacc = (float*)(ws + 42008576);
  float* beta = (float*)(ws + 42024960);

  k_prep    <<<dim3(4112),     dim3(256), 0, stream>>>(x, W1, b2, b3, xb, w1t, aacc, svec, uacc);
  k_gemm1   <<<dim3(1024),     dim3(256), 0, stream>>>(xb, w1t, b1, Abf, aacc);
  k_gemv_at <<<dim3(4, 64),    dim3(256), 0, stream>>>(W2, aacc, svec);
  k_gemv_row<<<dim3(1025),     dim3(256), 0, stream>>>(W2, svec, b2, tvec, beta);
  k_kv      <<<dim3(1024),     dim3(256), 0, stream>>>(Abf, tvec, beta, kvv);
  k_gemv_at <<<dim3(4, 64),    dim3(256), 0, stream>>>(W3, kvv, uacc);
  k_final   <<<dim3(1),        dim3(256), 0, stream>>>(uacc, W4, b4, out);
}